// Round 4
// baseline (19139.880 us; speedup 1.0000x reference)
//
#include <hip/hip_runtime.h>
#include <hip/hip_bf16.h>

#define TLEN 512
#define NB   32
#define HID  768
#define G4   3072

typedef __attribute__((ext_vector_type(8))) short bf16x8;
typedef __attribute__((ext_vector_type(4))) float f32x4;
typedef unsigned short u16;
typedef unsigned int u32;

__device__ __forceinline__ float bf2f(u16 u) {
  u32 t = ((u32)u) << 16; float f; __builtin_memcpy(&f, &t, 4); return f;
}
__device__ __forceinline__ u16 f2bf(float f) {
  u32 t; __builtin_memcpy(&t, &f, 4);
  u32 r = t + 0x7FFFu + ((t >> 16) & 1u);
  return (u16)(r >> 16);
}
// dual-dtype scalar loads: f!=0 -> input buffer is fp32, else packed bf16
__device__ __forceinline__ u16 ldbf(const void* p, size_t i, u32 f) {
  return f ? f2bf(((const float*)p)[i]) : ((const u16*)p)[i];
}
__device__ __forceinline__ float ldf(const void* p, size_t i, u32 f) {
  return f ? ((const float*)p)[i] : bf2f(((const u16*)p)[i]);
}
__device__ __forceinline__ float sigm(float x) { return 1.0f / (1.0f + __expf(-x)); }
__device__ __forceinline__ float tanh_(float x) { return 1.0f - 2.0f / (1.0f + __expf(2.0f * x)); }

// ---------------- prologue: dtype sniff + h0/c0 conversion -------------------
// fp32 data read as u16 pairs: low-half words have uniform exponent-field bits;
// packed-bf16 data: every u16 is a real bf16 with exponent ~in [100,140].
__global__ __launch_bounds__(256) void prologue(const void* __restrict__ x,
                                                const void* __restrict__ h0,
                                                const void* __restrict__ c0,
                                                u32* __restrict__ flag,
                                                u16* __restrict__ h0b,
                                                float* __restrict__ c0f) {
  __shared__ u32 sflag;
  if (threadIdx.x == 0) {
    const u32* w = (const u32*)x;
    int cnt = 0;
    for (int m = 0; m < 256; ++m) {
      u32 e = ((w[m] & 0xFFFFu) >> 7) & 0xFFu;  // low-half word's bf16-exponent field
      cnt += (e >= 100u && e <= 140u) ? 1 : 0;
    }
    sflag = (cnt >= 128) ? 0u : 1u;  // 1 = fp32 inputs
    flag[0] = sflag;
  }
  __syncthreads();
  const u32 f = sflag;
  for (int i = threadIdx.x; i < NB * HID; i += 256) {
    h0b[i] = ldbf(h0, i, f);
    c0f[i] = ldf(c0, i, f);
  }
}

// ---------------- transpose (R x C row-major -> C x R, emits bf16) ----------
__global__ __launch_bounds__(256) void transpose_any(const void* __restrict__ in,
                                                     u16* __restrict__ out, int R, int C,
                                                     const u32* __restrict__ flag) {
  const u32 f = flag[0];
  __shared__ u16 tile[64][65];
  int c0 = blockIdx.x * 64, r0 = blockIdx.y * 64;
  int tx = threadIdx.x & 63, ty = threadIdx.x >> 6;
#pragma unroll
  for (int j = 0; j < 16; ++j) {
    int r = ty + 4 * j;
    tile[r][tx] = ldbf(in, (size_t)(r0 + r) * C + c0 + tx, f);
  }
  __syncthreads();
#pragma unroll
  for (int j = 0; j < 16; ++j) {
    int r = ty + 4 * j;
    out[(size_t)(c0 + r) * R + r0 + tx] = tile[tx][r];
  }
}

// ---------------- QKV precompute: [16384 x 768] @ [768 x 2304] --------------
__global__ __launch_bounds__(256) void qkv_gemm(const void* __restrict__ X, const u16* __restrict__ WT,
                                                const void* __restrict__ bq, const void* __restrict__ bk,
                                                const void* __restrict__ bv,
                                                u16* __restrict__ Qx, u16* __restrict__ Kx,
                                                u16* __restrict__ Vx, const u32* __restrict__ flag) {
  const u32 f = flag[0];
  __shared__ __align__(16) u16 As[128][40];
  __shared__ __align__(16) u16 Bs[128][40];
  const int m0 = blockIdx.x * 128;
  const int n0 = blockIdx.y * 128;
  const int tid = threadIdx.x;
  const int lane = tid & 63, w = tid >> 6;
  const int l15 = lane & 15, l4 = lane >> 4;
  f32x4 zero4 = {0.f, 0.f, 0.f, 0.f};
  f32x4 acc[2][8];
#pragma unroll
  for (int h = 0; h < 2; ++h)
#pragma unroll
    for (int nt = 0; nt < 8; ++nt) acc[h][nt] = zero4;
  const int srow = tid >> 1, skp = (tid & 1) * 16;
  for (int k0 = 0; k0 < 768; k0 += 32) {
    __syncthreads();
    if (f) {
      const float* Xf = (const float*)X + (size_t)(m0 + srow) * 768 + k0 + skp;
#pragma unroll
      for (int q = 0; q < 16; ++q) As[srow][skp + q] = f2bf(Xf[q]);
    } else {
      const u16* Xh = (const u16*)X + (size_t)(m0 + srow) * 768 + k0 + skp;
      *(bf16x8*)&As[srow][skp]     = *(const bf16x8*)(Xh);
      *(bf16x8*)&As[srow][skp + 8] = *(const bf16x8*)(Xh + 8);
    }
    *(bf16x8*)&Bs[srow][skp]     = *(const bf16x8*)(WT + (size_t)(n0 + srow) * 768 + k0 + skp);
    *(bf16x8*)&Bs[srow][skp + 8] = *(const bf16x8*)(WT + (size_t)(n0 + srow) * 768 + k0 + skp + 8);
    __syncthreads();
    const int kl = 8 * l4;
    bf16x8 a0 = *(const bf16x8*)&As[32 * w + l15][kl];
    bf16x8 a1 = *(const bf16x8*)&As[32 * w + 16 + l15][kl];
#pragma unroll
    for (int nt = 0; nt < 8; ++nt) {
      bf16x8 b = *(const bf16x8*)&Bs[16 * nt + l15][kl];
      acc[0][nt] = __builtin_amdgcn_mfma_f32_16x16x32_bf16(a0, b, acc[0][nt], 0, 0, 0);
      acc[1][nt] = __builtin_amdgcn_mfma_f32_16x16x32_bf16(a1, b, acc[1][nt], 0, 0, 0);
    }
  }
#pragma unroll
  for (int h = 0; h < 2; ++h)
#pragma unroll
    for (int nt = 0; nt < 8; ++nt)
#pragma unroll
      for (int r = 0; r < 4; ++r) {
        const int m = m0 + 32 * w + 16 * h + 4 * l4 + r;
        const int n = n0 + 16 * nt + l15;
        float bias; u16* dst;
        if (n < 768)       { bias = ldf(bq, n, f);        dst = Qx + (size_t)m * 768 + n; }
        else if (n < 1536) { bias = ldf(bk, n - 768, f);  dst = Kx + (size_t)m * 768 + (n - 768); }
        else               { bias = ldf(bv, n - 1536, f); dst = Vx + (size_t)m * 768 + (n - 1536); }
        *dst = f2bf(acc[h][nt][r] + bias);
      }
}

// ---------------- persistent sequential scan (2-phase per step) --------------
struct ScanParams {
  const void *x, *bih, *bhh, *bk, *bv;   // raw inputs (dtype per flag)
  const u16 *h0b;                        // pre-converted bf16
  const float *c0f;                      // pre-converted fp32
  const int* ping;
  const u16 *WihT, *WhhT, *WqkvT;
  const u16 *Qx;
  u16 *Kx, *Vx;
  u16 *rowbuf, *hsb;                     // hsb: 2 ping-pong h buffers (bf16)
  void* out;                             // d_out (dtype per flag)
  u32 *ctr;
  const u32* flag;
};

// 240 blocks, 8 counters spaced 128B, 30 arrivals each per barrier.
__device__ __forceinline__ void gbarrier(u32* ctr, int bid, u32 target) {
  __threadfence();  // release
  if (threadIdx.x == 0) atomicAdd(&ctr[(bid & 7) * 32], 1u);
  for (;;) {
    u32 mine = target;
    if (threadIdx.x < 8)
      mine = __hip_atomic_load(&ctr[threadIdx.x * 32], __ATOMIC_RELAXED, __HIP_MEMORY_SCOPE_AGENT);
    if (__all(mine >= target)) break;
    __builtin_amdgcn_s_sleep(8);
  }
  __threadfence();  // acquire
}

__global__ __launch_bounds__(64, 1) void scan_kernel(ScanParams P) {
  const int bid = blockIdx.x;
  const int lane = threadIdx.x;
  const int l15 = lane & 15, l4 = lane >> 4;
  const u32 f = P.flag[0];
  u32 z = 1;

  if (bid < 192) {
    // ------- gates wave: 16 tile-cols = {jb+jl} x {i,f,g,o blocks}, K=1536 -------
    const int jb = 4 * bid;
    const int q_ = l15 >> 2, jl = l15 & 3;
    const int colW = 768 * q_ + jb + jl;
    bf16x8 Bfr[48];
#pragma unroll
    for (int s = 0; s < 48; ++s) {
      int k = 32 * s + 8 * l4;
      const u16* src = (s < 24) ? (P.WihT + (size_t)colW * HID + k)
                                : (P.WhhT + (size_t)colW * HID + (k - 768));
      Bfr[s] = *(const bf16x8*)src;
    }
    const float biasv = ldf(P.bih, colW, f) + ldf(P.bhh, colW, f);
    const int cb = lane >> 1, cj = 2 * (lane & 1);
    float cst0 = P.c0f[(size_t)cb * HID + jb + cj];
    float cst1 = P.c0f[(size_t)cb * HID + jb + cj + 1];
    __shared__ float gbuf[32][4][4];

    for (int i = 0; i < TLEN; ++i) {
      gbarrier(P.ctr, bid, 30u * z); ++z;  // end of phase A: row_i published
      const u16* rowp = P.rowbuf;
      const u16* hp = (i == 0) ? P.h0b : (P.hsb + (size_t)((i - 1) & 1) * NB * HID);
      f32x4 acc0 = {0.f, 0.f, 0.f, 0.f}, acc1 = {0.f, 0.f, 0.f, 0.f};
#pragma unroll
      for (int s = 0; s < 48; ++s) {
        int k = 32 * s + 8 * l4;
        const u16* base = (s < 24) ? (rowp + k) : (hp + (k - 768));
        bf16x8 a0 = *(const bf16x8*)(base + (size_t)l15 * HID);
        bf16x8 a1 = *(const bf16x8*)(base + (size_t)(l15 + 16) * HID);
        acc0 = __builtin_amdgcn_mfma_f32_16x16x32_bf16(a0, Bfr[s], acc0, 0, 0, 0);
        acc1 = __builtin_amdgcn_mfma_f32_16x16x32_bf16(a1, Bfr[s], acc1, 0, 0, 0);
      }
#pragma unroll
      for (int r = 0; r < 4; ++r) {
        gbuf[4 * l4 + r][q_][jl] = acc0[r] + biasv;
        gbuf[16 + 4 * l4 + r][q_][jl] = acc1[r] + biasv;
      }
      __syncthreads();
      float ig0 = gbuf[cb][0][cj],     fg0 = gbuf[cb][1][cj];
      float gg0 = gbuf[cb][2][cj],     og0 = gbuf[cb][3][cj];
      float ig1 = gbuf[cb][0][cj + 1], fg1 = gbuf[cb][1][cj + 1];
      float gg1 = gbuf[cb][2][cj + 1], og1 = gbuf[cb][3][cj + 1];
      __syncthreads();
      cst0 = sigm(fg0) * cst0 + sigm(ig0) * tanh_(gg0);
      cst1 = sigm(fg1) * cst1 + sigm(ig1) * tanh_(gg1);
      float h0v = sigm(og0) * tanh_(cst0);
      float h1v = sigm(og1) * tanh_(cst1);
      // bf16 copy for the recurrence
      u16* hb = P.hsb + (size_t)(i & 1) * NB * HID + (size_t)cb * HID + jb + cj;
      hb[0] = f2bf(h0v); hb[1] = f2bf(h1v);
      // output hs (dtype per flag), element offsets
      const size_t o1 = (size_t)i * NB * HID + (size_t)cb * HID + jb + cj;
      if (f) { float* O = (float*)P.out; O[o1] = h0v; O[o1 + 1] = h1v; }
      else   { u16*   O = (u16*)P.out;   O[o1] = f2bf(h0v); O[o1 + 1] = f2bf(h1v); }
      if (i == TLEN - 1) {
        const size_t oh = (size_t)TLEN * NB * HID + (size_t)cb * HID + jb + cj;
        const size_t oc = (size_t)(TLEN + 1) * NB * HID + (size_t)cb * HID + jb + cj;
        if (f) { float* O = (float*)P.out; O[oh] = h0v; O[oh + 1] = h1v; O[oc] = cst0; O[oc + 1] = cst1; }
        else   { u16*   O = (u16*)P.out;   O[oh] = f2bf(h0v); O[oh + 1] = f2bf(h1v);
                 O[oc] = f2bf(cst0); O[oc + 1] = f2bf(cst1); }
      }
      gbarrier(P.ctr, bid, 30u * z); ++z;  // end of phase B
    }
  } else {
    // ------- k/v wave (32 cols, K=768); first 32 also run attention in phase A ---
    const int v = bid - 192;
    const int col0 = 32 * v;
    const bool isV = (col0 >= 768);
    const u16* Wt = P.WqkvT + (size_t)(768 + col0) * HID;  // wk^T rows 768.., wv^T rows 1536..
    const int oc0 = isV ? (col0 - 768) : col0;
    u16* obase = isV ? P.Vx : P.Kx;
    const void* bias_src = isV ? P.bv : P.bk;
    const float bias0 = ldf(bias_src, oc0 + l15, f);
    const float bias1 = ldf(bias_src, oc0 + 16 + l15, f);
    bf16x8 Bfr[48];
#pragma unroll
    for (int s = 0; s < 24; ++s) {
      int k = 32 * s + 8 * l4;
      Bfr[2 * s]     = *(const bf16x8*)(Wt + (size_t)l15 * HID + k);
      Bfr[2 * s + 1] = *(const bf16x8*)(Wt + (size_t)(16 + l15) * HID + k);
    }
    const bool doAttn = (v < NB);

    for (int i = 0; i < TLEN; ++i) {
      // ---- phase A: attention computes row_i (batch v) ----
      if (doAttn) {
        const int b = v;
        const int p = (i == 0) ? 0 : P.ping[(size_t)b * TLEN + i];
        u16* orow = P.rowbuf + (size_t)b * HID;
        if (p == 0) {  // mask false -> row = x[i]
          const size_t xoff = ((size_t)i * NB + b) * HID;
#pragma unroll
          for (int j = 0; j < 12; ++j) orow[64 * j + lane] = ldbf(P.x, xoff + 64 * j + lane, f);
        } else {
          const int idx = p - 1;  // [0,510]
          const u16* kL = P.Kx + ((size_t)idx * NB + b) * HID;
          const u16* vL = P.Vx + ((size_t)idx * NB + b) * HID;
          const u16* qp = P.Qx + ((size_t)i * NB + b) * HID;
          const u16* kR = P.Kx + ((size_t)i * NB + b) * HID;
          const u16* vR = P.Vx + ((size_t)i * NB + b) * HID;
          float d0[12], d1[12];
#pragma unroll
          for (int j = 0; j < 12; ++j) {
            float qv = bf2f(qp[64 * j + lane]);
            d0[j] = qv * bf2f(kL[64 * j + lane]);
            d1[j] = qv * bf2f(kR[64 * j + lane]);
          }
#pragma unroll
          for (int m = 32; m > 0; m >>= 1) {
#pragma unroll
            for (int j = 0; j < 12; ++j) {
              d0[j] += __shfl_xor(d0[j], m);
              d1[j] += __shfl_xor(d1[j], m);
            }
          }
#pragma unroll
          for (int j = 0; j < 12; ++j) {
            float pw0 = sigm((d0[j] - d1[j]) * 0.125f);  // softmax over 2 keys
            float ov = pw0 * bf2f(vL[64 * j + lane]) + (1.0f - pw0) * bf2f(vR[64 * j + lane]);
            orow[64 * j + lane] = f2bf(ov);
          }
        }
      }
      gbarrier(P.ctr, bid, 30u * z); ++z;  // end of phase A

      // ---- phase B: project row_i -> Kx[i]/Vx[i] (no concurrent reader) ----
      const u16* rowp = P.rowbuf;
      f32x4 a00 = {0.f,0.f,0.f,0.f}, a01 = {0.f,0.f,0.f,0.f};
      f32x4 a10 = {0.f,0.f,0.f,0.f}, a11 = {0.f,0.f,0.f,0.f};
#pragma unroll
      for (int s = 0; s < 24; ++s) {
        int k = 32 * s + 8 * l4;
        bf16x8 r0 = *(const bf16x8*)(rowp + (size_t)l15 * HID + k);
        bf16x8 r1 = *(const bf16x8*)(rowp + (size_t)(l15 + 16) * HID + k);
        a00 = __builtin_amdgcn_mfma_f32_16x16x32_bf16(r0, Bfr[2 * s],     a00, 0, 0, 0);
        a01 = __builtin_amdgcn_mfma_f32_16x16x32_bf16(r0, Bfr[2 * s + 1], a01, 0, 0, 0);
        a10 = __builtin_amdgcn_mfma_f32_16x16x32_bf16(r1, Bfr[2 * s],     a10, 0, 0, 0);
        a11 = __builtin_amdgcn_mfma_f32_16x16x32_bf16(r1, Bfr[2 * s + 1], a11, 0, 0, 0);
      }
      u16* ob = obase + (size_t)i * NB * HID + oc0;
#pragma unroll
      for (int r = 0; r < 4; ++r) {
        int b0 = 4 * l4 + r;
        ob[(size_t)b0 * HID + l15]             = f2bf(a00[r] + bias0);
        ob[(size_t)b0 * HID + 16 + l15]        = f2bf(a01[r] + bias1);
        ob[(size_t)(16 + b0) * HID + l15]      = f2bf(a10[r] + bias0);
        ob[(size_t)(16 + b0) * HID + 16 + l15] = f2bf(a11[r] + bias1);
      }
      gbarrier(P.ctr, bid, 30u * z); ++z;  // end of phase B
    }
  }
}

extern "C" void kernel_launch(void* const* d_in, const int* in_sizes, int n_in,
                              void* d_out, int out_size, void* d_ws, size_t ws_size,
                              hipStream_t stream) {
  const void* x   = d_in[0];
  const int* ping = (const int*)d_in[1];
  const void* h0  = d_in[2];
  const void* c0  = d_in[3];
  const void* wih = d_in[4];
  const void* whh = d_in[5];
  const void* bih = d_in[6];
  const void* bhh = d_in[7];
  const void* wq  = d_in[8];
  const void* bq  = d_in[9];
  const void* wk  = d_in[10];
  const void* bk  = d_in[11];
  const void* wv  = d_in[12];
  const void* bv  = d_in[13];
  (void)in_sizes; (void)n_in; (void)out_size; (void)ws_size;  // needs ~90 MB ws

  char* ws = (char*)d_ws;
  size_t off = 0;
  auto walloc = [&](size_t b) { char* p = ws + off; off += (b + 255) & ~(size_t)255; return p; };
  u32* ctr    = (u32*)walloc(2048);
  u32* flag   = ctr + 300;  // within the 2048B ctr region, away from counters
  u16* WqkvT  = (u16*)walloc((size_t)2304 * 768 * 2);
  u16* WihT   = (u16*)walloc((size_t)3072 * 768 * 2);
  u16* WhhT   = (u16*)walloc((size_t)3072 * 768 * 2);
  u16* Qx     = (u16*)walloc((size_t)TLEN * NB * HID * 2);
  u16* Kx     = (u16*)walloc((size_t)TLEN * NB * HID * 2);
  u16* Vx     = (u16*)walloc((size_t)TLEN * NB * HID * 2);
  u16* rowbuf = (u16*)walloc((size_t)NB * HID * 2);
  u16* h0b    = (u16*)walloc((size_t)NB * HID * 2);
  float* c0f  = (float*)walloc((size_t)NB * HID * 4);
  u16* hsb    = (u16*)walloc((size_t)2 * NB * HID * 2);

  hipMemsetAsync(ctr, 0, 2048, stream);
  prologue<<<1, 256, 0, stream>>>(x, h0, c0, flag, h0b, c0f);
  transpose_any<<<dim3(12, 12), 256, 0, stream>>>(wq, WqkvT, 768, 768, flag);
  transpose_any<<<dim3(12, 12), 256, 0, stream>>>(wk, WqkvT + (size_t)768 * 768, 768, 768, flag);
  transpose_any<<<dim3(12, 12), 256, 0, stream>>>(wv, WqkvT + (size_t)1536 * 768, 768, 768, flag);
  transpose_any<<<dim3(48, 12), 256, 0, stream>>>(wih, WihT, 768, 3072, flag);
  transpose_any<<<dim3(48, 12), 256, 0, stream>>>(whh, WhhT, 768, 3072, flag);
  qkv_gemm<<<dim3(128, 18), 256, 0, stream>>>(x, WqkvT, bq, bk, bv, Qx, Kx, Vx, flag);

  ScanParams P;
  P.x = x; P.bih = bih; P.bhh = bhh; P.bk = bk; P.bv = bv;
  P.h0b = h0b; P.c0f = c0f;
  P.ping = ping;
  P.WihT = WihT; P.WhhT = WhhT; P.WqkvT = WqkvT;
  P.Qx = Qx; P.Kx = Kx; P.Vx = Vx;
  P.rowbuf = rowbuf; P.hsb = hsb;
  P.out = d_out;
  P.ctr = ctr; P.flag = flag;
  scan_kernel<<<dim3(240), dim3(64), 0, stream>>>(P);
}

// Round 5
// 16113.643 us; speedup vs baseline: 1.1878x; 1.1878x over previous
//
#include <hip/hip_runtime.h>
#include <hip/hip_bf16.h>

#define TLEN 512
#define NB   32
#define HID  768
#define G4   3072

typedef __attribute__((ext_vector_type(8))) short bf16x8;
typedef __attribute__((ext_vector_type(4))) float f32x4;
typedef unsigned short u16;
typedef unsigned int u32;
typedef unsigned long long u64;

__device__ __forceinline__ float bf2f(u16 u) {
  u32 t = ((u32)u) << 16; float f; __builtin_memcpy(&f, &t, 4); return f;
}
__device__ __forceinline__ u16 f2bf(float f) {
  u32 t; __builtin_memcpy(&t, &f, 4);
  u32 r = t + 0x7FFFu + ((t >> 16) & 1u);
  return (u16)(r >> 16);
}
// dual-dtype scalar loads: f!=0 -> input buffer is fp32, else packed bf16
__device__ __forceinline__ u16 ldbf(const void* p, size_t i, u32 f) {
  return f ? f2bf(((const float*)p)[i]) : ((const u16*)p)[i];
}
__device__ __forceinline__ float ldf(const void* p, size_t i, u32 f) {
  return f ? ((const float*)p)[i] : bf2f(((const u16*)p)[i]);
}
__device__ __forceinline__ float sigm(float x) { return 1.0f / (1.0f + __expf(-x)); }
__device__ __forceinline__ float tanh_(float x) { return 1.0f - 2.0f / (1.0f + __expf(2.0f * x)); }

// ---- agent-scope (cross-XCD coherent, IF$-point) accesses: bypass stale L2 ----
__device__ __forceinline__ u64 cld64(const u16* p) {
  return __hip_atomic_load((const u64*)p, __ATOMIC_RELAXED, __HIP_MEMORY_SCOPE_AGENT);
}
__device__ __forceinline__ void cst64(u16* p, u64 v) {
  __hip_atomic_store((u64*)p, v, __ATOMIC_RELAXED, __HIP_MEMORY_SCOPE_AGENT);
}
__device__ __forceinline__ bf16x8 cld128(const u16* p) {
  union { u64 q[2]; bf16x8 v; } u;
  u.q[0] = cld64(p); u.q[1] = cld64(p + 4);
  return u.v;
}

// ---------------- prologue: dtype sniff + h0/c0 conversion -------------------
__global__ __launch_bounds__(256) void prologue(const void* __restrict__ x,
                                                const void* __restrict__ h0,
                                                const void* __restrict__ c0,
                                                u32* __restrict__ flag,
                                                u16* __restrict__ h0b,
                                                float* __restrict__ c0f) {
  __shared__ u32 sflag;
  if (threadIdx.x == 0) {
    const u32* w = (const u32*)x;
    int cnt = 0;
    for (int m = 0; m < 256; ++m) {
      u32 e = ((w[m] & 0xFFFFu) >> 7) & 0xFFu;
      cnt += (e >= 100u && e <= 140u) ? 1 : 0;
    }
    sflag = (cnt >= 128) ? 0u : 1u;  // 1 = fp32 inputs
    flag[0] = sflag;
  }
  __syncthreads();
  const u32 f = sflag;
  for (int i = threadIdx.x; i < NB * HID; i += 256) {
    h0b[i] = ldbf(h0, i, f);
    c0f[i] = ldf(c0, i, f);
  }
}

// ---------------- transpose (R x C row-major -> C x R, emits bf16) ----------
__global__ __launch_bounds__(256) void transpose_any(const void* __restrict__ in,
                                                     u16* __restrict__ out, int R, int C,
                                                     const u32* __restrict__ flag) {
  const u32 f = flag[0];
  __shared__ u16 tile[64][65];
  int c0 = blockIdx.x * 64, r0 = blockIdx.y * 64;
  int tx = threadIdx.x & 63, ty = threadIdx.x >> 6;
#pragma unroll
  for (int j = 0; j < 16; ++j) {
    int r = ty + 4 * j;
    tile[r][tx] = ldbf(in, (size_t)(r0 + r) * C + c0 + tx, f);
  }
  __syncthreads();
#pragma unroll
  for (int j = 0; j < 16; ++j) {
    int r = ty + 4 * j;
    out[(size_t)(c0 + r) * R + r0 + tx] = tile[tx][r];
  }
}

// ---------------- QKV precompute: [16384 x 768] @ [768 x 2304] --------------
__global__ __launch_bounds__(256) void qkv_gemm(const void* __restrict__ X, const u16* __restrict__ WT,
                                                const void* __restrict__ bq, const void* __restrict__ bk,
                                                const void* __restrict__ bv,
                                                u16* __restrict__ Qx, u16* __restrict__ Kx,
                                                u16* __restrict__ Vx, const u32* __restrict__ flag) {
  const u32 f = flag[0];
  __shared__ __align__(16) u16 As[128][40];
  __shared__ __align__(16) u16 Bs[128][40];
  const int m0 = blockIdx.x * 128;
  const int n0 = blockIdx.y * 128;
  const int tid = threadIdx.x;
  const int lane = tid & 63, w = tid >> 6;
  const int l15 = lane & 15, l4 = lane >> 4;
  f32x4 zero4 = {0.f, 0.f, 0.f, 0.f};
  f32x4 acc[2][8];
#pragma unroll
  for (int h = 0; h < 2; ++h)
#pragma unroll
    for (int nt = 0; nt < 8; ++nt) acc[h][nt] = zero4;
  const int srow = tid >> 1, skp = (tid & 1) * 16;
  for (int k0 = 0; k0 < 768; k0 += 32) {
    __syncthreads();
    if (f) {
      const float* Xf = (const float*)X + (size_t)(m0 + srow) * 768 + k0 + skp;
#pragma unroll
      for (int q = 0; q < 16; ++q) As[srow][skp + q] = f2bf(Xf[q]);
    } else {
      const u16* Xh = (const u16*)X + (size_t)(m0 + srow) * 768 + k0 + skp;
      *(bf16x8*)&As[srow][skp]     = *(const bf16x8*)(Xh);
      *(bf16x8*)&As[srow][skp + 8] = *(const bf16x8*)(Xh + 8);
    }
    *(bf16x8*)&Bs[srow][skp]     = *(const bf16x8*)(WT + (size_t)(n0 + srow) * 768 + k0 + skp);
    *(bf16x8*)&Bs[srow][skp + 8] = *(const bf16x8*)(WT + (size_t)(n0 + srow) * 768 + k0 + skp + 8);
    __syncthreads();
    const int kl = 8 * l4;
    bf16x8 a0 = *(const bf16x8*)&As[32 * w + l15][kl];
    bf16x8 a1 = *(const bf16x8*)&As[32 * w + 16 + l15][kl];
#pragma unroll
    for (int nt = 0; nt < 8; ++nt) {
      bf16x8 b = *(const bf16x8*)&Bs[16 * nt + l15][kl];
      acc[0][nt] = __builtin_amdgcn_mfma_f32_16x16x32_bf16(a0, b, acc[0][nt], 0, 0, 0);
      acc[1][nt] = __builtin_amdgcn_mfma_f32_16x16x32_bf16(a1, b, acc[1][nt], 0, 0, 0);
    }
  }
#pragma unroll
  for (int h = 0; h < 2; ++h)
#pragma unroll
    for (int nt = 0; nt < 8; ++nt)
#pragma unroll
      for (int r = 0; r < 4; ++r) {
        const int m = m0 + 32 * w + 16 * h + 4 * l4 + r;
        const int n = n0 + 16 * nt + l15;
        float bias; u16* dst;
        if (n < 768)       { bias = ldf(bq, n, f);        dst = Qx + (size_t)m * 768 + n; }
        else if (n < 1536) { bias = ldf(bk, n - 768, f);  dst = Kx + (size_t)m * 768 + (n - 768); }
        else               { bias = ldf(bv, n - 1536, f); dst = Vx + (size_t)m * 768 + (n - 1536); }
        *dst = f2bf(acc[h][nt][r] + bias);
      }
}

// ---------------- persistent sequential scan (2-phase per step) --------------
struct ScanParams {
  const void *x, *bih, *bhh, *bk, *bv;
  const u16 *h0b;
  const float *c0f;
  const int* ping;
  const u16 *WihT, *WhhT, *WqkvT;
  const u16 *Qx;
  u16 *Kx, *Vx;
  u16 *rowbuf, *hsb;
  void* out;
  u32 *ctr;
  const u32* flag;
};

// 240 single-wave blocks; 8 counters spaced 128B, 30 arrivals each per barrier.
// No cache-wide fences: all shared mutable data moves via agent-scope (sc1)
// accesses that are coherent at the IF$; s_waitcnt(0) orders stores before the
// counter add within the wave.
__device__ __forceinline__ void gbarrier(u32* ctr, int bid, u32 target) {
  __builtin_amdgcn_s_waitcnt(0);
  if (threadIdx.x == 0)
    __hip_atomic_fetch_add(&ctr[(bid & 7) * 32], 1u, __ATOMIC_RELAXED, __HIP_MEMORY_SCOPE_AGENT);
  for (;;) {
    u32 mine = target;
    if (threadIdx.x < 8)
      mine = __hip_atomic_load(&ctr[threadIdx.x * 32], __ATOMIC_RELAXED, __HIP_MEMORY_SCOPE_AGENT);
    if (__all(mine >= target)) break;
    __builtin_amdgcn_s_sleep(1);
  }
  asm volatile("" ::: "memory");
}

__global__ __launch_bounds__(64, 1) void scan_kernel(ScanParams P) {
  const int bid = blockIdx.x;
  const int lane = threadIdx.x;
  const int l15 = lane & 15, l4 = lane >> 4;
  const u32 f = P.flag[0];
  u32 z = 1;

  if (bid < 192) {
    // ------- gates wave: 16 tile-cols = {jb+jl} x {i,f,g,o blocks}, K=1536 -------
    const int jb = 4 * bid;
    const int q_ = l15 >> 2, jl = l15 & 3;
    const int colW = 768 * q_ + jb + jl;
    bf16x8 Bfr[48];
#pragma unroll
    for (int s = 0; s < 48; ++s) {
      int k = 32 * s + 8 * l4;
      const u16* src = (s < 24) ? (P.WihT + (size_t)colW * HID + k)
                                : (P.WhhT + (size_t)colW * HID + (k - 768));
      Bfr[s] = *(const bf16x8*)src;
    }
    const float biasv = ldf(P.bih, colW, f) + ldf(P.bhh, colW, f);
    const int cb = lane >> 1, cj = 2 * (lane & 1);
    float cst0 = P.c0f[(size_t)cb * HID + jb + cj];
    float cst1 = P.c0f[(size_t)cb * HID + jb + cj + 1];
    __shared__ float gbuf[32][4][4];
    __shared__ u16 htile[32][4];

    for (int i = 0; i < TLEN; ++i) {
      gbarrier(P.ctr, bid, 30u * z); ++z;  // end of phase A: row_i published
      const u16* rowp = P.rowbuf;
      const u16* hp = (i == 0) ? P.h0b : (P.hsb + (size_t)((i - 1) & 1) * NB * HID);
      f32x4 acc0 = {0.f, 0.f, 0.f, 0.f}, acc1 = {0.f, 0.f, 0.f, 0.f};
#pragma unroll
      for (int s = 0; s < 48; ++s) {
        int k = 32 * s + 8 * l4;
        const u16* base = (s < 24) ? (rowp + k) : (hp + (k - 768));
        bf16x8 a0 = cld128(base + (size_t)l15 * HID);
        bf16x8 a1 = cld128(base + (size_t)(l15 + 16) * HID);
        acc0 = __builtin_amdgcn_mfma_f32_16x16x32_bf16(a0, Bfr[s], acc0, 0, 0, 0);
        acc1 = __builtin_amdgcn_mfma_f32_16x16x32_bf16(a1, Bfr[s], acc1, 0, 0, 0);
      }
#pragma unroll
      for (int r = 0; r < 4; ++r) {
        gbuf[4 * l4 + r][q_][jl] = acc0[r] + biasv;
        gbuf[16 + 4 * l4 + r][q_][jl] = acc1[r] + biasv;
      }
      __syncthreads();
      float ig0 = gbuf[cb][0][cj],     fg0 = gbuf[cb][1][cj];
      float gg0 = gbuf[cb][2][cj],     og0 = gbuf[cb][3][cj];
      float ig1 = gbuf[cb][0][cj + 1], fg1 = gbuf[cb][1][cj + 1];
      float gg1 = gbuf[cb][2][cj + 1], og1 = gbuf[cb][3][cj + 1];
      __syncthreads();
      cst0 = sigm(fg0) * cst0 + sigm(ig0) * tanh_(gg0);
      cst1 = sigm(fg1) * cst1 + sigm(ig1) * tanh_(gg1);
      float h0v = sigm(og0) * tanh_(cst0);
      float h1v = sigm(og1) * tanh_(cst1);
      // h recurrence: pack 4 cols/batch into u64, coherent store (lanes < 32)
      htile[cb][cj] = f2bf(h0v); htile[cb][cj + 1] = f2bf(h1v);
      __syncthreads();
      if (lane < 32) {
        u64 hv; __builtin_memcpy(&hv, &htile[lane][0], 8);
        cst64(P.hsb + (size_t)(i & 1) * NB * HID + (size_t)lane * HID + jb, hv);
      }
      // output hs (dtype per flag), plain stores (flushed at kernel end)
      const size_t o1 = (size_t)i * NB * HID + (size_t)cb * HID + jb + cj;
      if (f) { float* O = (float*)P.out; O[o1] = h0v; O[o1 + 1] = h1v; }
      else   { u16*   O = (u16*)P.out;   O[o1] = f2bf(h0v); O[o1 + 1] = f2bf(h1v); }
      if (i == TLEN - 1) {
        const size_t oh = (size_t)TLEN * NB * HID + (size_t)cb * HID + jb + cj;
        const size_t oc = (size_t)(TLEN + 1) * NB * HID + (size_t)cb * HID + jb + cj;
        if (f) { float* O = (float*)P.out; O[oh] = h0v; O[oh + 1] = h1v; O[oc] = cst0; O[oc + 1] = cst1; }
        else   { u16*   O = (u16*)P.out;   O[oh] = f2bf(h0v); O[oh + 1] = f2bf(h1v);
                 O[oc] = f2bf(cst0); O[oc + 1] = f2bf(cst1); }
      }
      gbarrier(P.ctr, bid, 30u * z); ++z;  // end of phase B
    }
  } else {
    // ------- k/v wave (32 cols, K=768); first 32 also run attention in phase A ---
    const int v = bid - 192;
    const int col0 = 32 * v;
    const bool isV = (col0 >= 768);
    const u16* Wt = P.WqkvT + (size_t)(768 + col0) * HID;
    const int oc0 = isV ? (col0 - 768) : col0;
    u16* obase = isV ? P.Vx : P.Kx;
    const void* bias_src = isV ? P.bv : P.bk;
    const float bias0 = ldf(bias_src, oc0 + l15, f);
    const float bias1 = ldf(bias_src, oc0 + 16 + l15, f);
    bf16x8 Bfr[48];
#pragma unroll
    for (int s = 0; s < 24; ++s) {
      int k = 32 * s + 8 * l4;
      Bfr[2 * s]     = *(const bf16x8*)(Wt + (size_t)l15 * HID + k);
      Bfr[2 * s + 1] = *(const bf16x8*)(Wt + (size_t)(16 + l15) * HID + k);
    }
    const bool doAttn = (v < NB);
    __shared__ __align__(8) u16 sbuf[3][HID];   // attn: kL / vL / row-out staging
    __shared__ __align__(8) u16 tile[32][32];   // kv: output bounce

    for (int i = 0; i < TLEN; ++i) {
      // ---- phase A: attention computes row_i (batch v) ----
      if (doAttn) {
        const int b = v;
        const int p = (i == 0) ? 0 : P.ping[(size_t)b * TLEN + i];
        u16* orow = P.rowbuf + (size_t)b * HID;
        if (p == 0) {  // mask false -> row = x[i]; pack 12 contiguous, coherent store
          const size_t xoff = ((size_t)i * NB + b) * HID + 12 * lane;
#pragma unroll
          for (int q = 0; q < 3; ++q) {
            u16 e[4];
#pragma unroll
            for (int t2 = 0; t2 < 4; ++t2) e[t2] = ldbf(P.x, xoff + 4 * q + t2, f);
            u64 w8; __builtin_memcpy(&w8, e, 8);
            cst64(orow + 12 * lane + 4 * q, w8);
          }
        } else {
          const int idx = p - 1;
          const u16* kL = P.Kx + ((size_t)idx * NB + b) * HID;
          const u16* vL = P.Vx + ((size_t)idx * NB + b) * HID;
          // stage kL/vL via coherent u64 loads (12 contiguous u16 per lane)
#pragma unroll
          for (int q = 0; q < 3; ++q) {
            *(u64*)&sbuf[0][12 * lane + 4 * q] = cld64(kL + 12 * lane + 4 * q);
            *(u64*)&sbuf[1][12 * lane + 4 * q] = cld64(vL + 12 * lane + 4 * q);
          }
          const u16* qp = P.Qx + ((size_t)i * NB + b) * HID;  // read-only: cached
          const u16* kR = P.Kx + ((size_t)i * NB + b) * HID;  // pre-overwrite: cached ok
          const u16* vR = P.Vx + ((size_t)i * NB + b) * HID;
          __syncthreads();
          float d0[12], d1[12];
#pragma unroll
          for (int j = 0; j < 12; ++j) {  // head j = cols [64j, 64j+64)
            float qv = bf2f(qp[64 * j + lane]);
            d0[j] = qv * bf2f(sbuf[0][64 * j + lane]);
            d1[j] = qv * bf2f(kR[64 * j + lane]);
          }
#pragma unroll
          for (int m = 32; m > 0; m >>= 1) {
#pragma unroll
            for (int j = 0; j < 12; ++j) {
              d0[j] += __shfl_xor(d0[j], m);
              d1[j] += __shfl_xor(d1[j], m);
            }
          }
#pragma unroll
          for (int j = 0; j < 12; ++j) {
            float pw0 = sigm((d0[j] - d1[j]) * 0.125f);  // softmax over 2 keys
            float ov = pw0 * bf2f(sbuf[1][64 * j + lane]) + (1.0f - pw0) * bf2f(vR[64 * j + lane]);
            sbuf[2][64 * j + lane] = f2bf(ov);
          }
          __syncthreads();
#pragma unroll
          for (int q = 0; q < 3; ++q) {
            u64 w8; __builtin_memcpy(&w8, &sbuf[2][12 * lane + 4 * q], 8);
            cst64(orow + 12 * lane + 4 * q, w8);
          }
        }
      }
      gbarrier(P.ctr, bid, 30u * z); ++z;  // end of phase A

      // ---- phase B: project row_i -> Kx[i]/Vx[i] (no concurrent reader) ----
      const u16* rowp = P.rowbuf;
      f32x4 a00 = {0.f,0.f,0.f,0.f}, a01 = {0.f,0.f,0.f,0.f};
      f32x4 a10 = {0.f,0.f,0.f,0.f}, a11 = {0.f,0.f,0.f,0.f};
#pragma unroll
      for (int s = 0; s < 24; ++s) {
        int k = 32 * s + 8 * l4;
        bf16x8 r0 = cld128(rowp + (size_t)l15 * HID + k);
        bf16x8 r1 = cld128(rowp + (size_t)(l15 + 16) * HID + k);
        a00 = __builtin_amdgcn_mfma_f32_16x16x32_bf16(r0, Bfr[2 * s],     a00, 0, 0, 0);
        a01 = __builtin_amdgcn_mfma_f32_16x16x32_bf16(r0, Bfr[2 * s + 1], a01, 0, 0, 0);
        a10 = __builtin_amdgcn_mfma_f32_16x16x32_bf16(r1, Bfr[2 * s],     a10, 0, 0, 0);
        a11 = __builtin_amdgcn_mfma_f32_16x16x32_bf16(r1, Bfr[2 * s + 1], a11, 0, 0, 0);
      }
      // bounce 32x32 output tile through LDS, then coherent u64 stores
#pragma unroll
      for (int r = 0; r < 4; ++r) {
        int b0 = 4 * l4 + r;
        tile[b0][l15]           = f2bf(a00[r] + bias0);
        tile[b0][16 + l15]      = f2bf(a01[r] + bias1);
        tile[16 + b0][l15]      = f2bf(a10[r] + bias0);
        tile[16 + b0][16 + l15] = f2bf(a11[r] + bias1);
      }
      __syncthreads();
      {
        u16* ob = obase + (size_t)i * NB * HID + oc0;
        const int row = lane >> 1, ch = (lane & 1) * 16;
#pragma unroll
        for (int q = 0; q < 4; ++q) {
          u64 w8; __builtin_memcpy(&w8, &tile[row][ch + 4 * q], 8);
          cst64(ob + (size_t)row * HID + ch + 4 * q, w8);
        }
      }
      __syncthreads();
      gbarrier(P.ctr, bid, 30u * z); ++z;  // end of phase B
    }
  }
}

extern "C" void kernel_launch(void* const* d_in, const int* in_sizes, int n_in,
                              void* d_out, int out_size, void* d_ws, size_t ws_size,
                              hipStream_t stream) {
  const void* x   = d_in[0];
  const int* ping = (const int*)d_in[1];
  const void* h0  = d_in[2];
  const void* c0  = d_in[3];
  const void* wih = d_in[4];
  const void* whh = d_in[5];
  const void* bih = d_in[6];
  const void* bhh = d_in[7];
  const void* wq  = d_in[8];
  const void* bq  = d_in[9];
  const void* wk  = d_in[10];
  const void* bk  = d_in[11];
  const void* wv  = d_in[12];
  const void* bv  = d_in[13];
  (void)in_sizes; (void)n_in; (void)out_size; (void)ws_size;  // needs ~90 MB ws

  char* ws = (char*)d_ws;
  size_t off = 0;
  auto walloc = [&](size_t b) { char* p = ws + off; off += (b + 255) & ~(size_t)255; return p; };
  u32* ctr    = (u32*)walloc(2048);
  u32* flag   = ctr + 300;
  u16* WqkvT  = (u16*)walloc((size_t)2304 * 768 * 2);
  u16* WihT   = (u16*)walloc((size_t)3072 * 768 * 2);
  u16* WhhT   = (u16*)walloc((size_t)3072 * 768 * 2);
  u16* Qx     = (u16*)walloc((size_t)TLEN * NB * HID * 2);
  u16* Kx     = (u16*)walloc((size_t)TLEN * NB * HID * 2);
  u16* Vx     = (u16*)walloc((size_t)TLEN * NB * HID * 2);
  u16* rowbuf = (u16*)walloc((size_t)NB * HID * 2);
  u16* h0b    = (u16*)walloc((size_t)NB * HID * 2);
  float* c0f  = (float*)walloc((size_t)NB * HID * 4);
  u16* hsb    = (u16*)walloc((size_t)2 * NB * HID * 2);

  hipMemsetAsync(ctr, 0, 2048, stream);
  prologue<<<1, 256, 0, stream>>>(x, h0, c0, flag, h0b, c0f);
  transpose_any<<<dim3(12, 12), 256, 0, stream>>>(wq, WqkvT, 768, 768, flag);
  transpose_any<<<dim3(12, 12), 256, 0, stream>>>(wk, WqkvT + (size_t)768 * 768, 768, 768, flag);
  transpose_any<<<dim3(12, 12), 256, 0, stream>>>(wv, WqkvT + (size_t)1536 * 768, 768, 768, flag);
  transpose_any<<<dim3(48, 12), 256, 0, stream>>>(wih, WihT, 768, 3072, flag);
  transpose_any<<<dim3(48, 12), 256, 0, stream>>>(whh, WhhT, 768, 3072, flag);
  qkv_gemm<<<dim3(128, 18), 256, 0, stream>>>(x, WqkvT, bq, bk, bv, Qx, Kx, Vx, flag);

  ScanParams P;
  P.x = x; P.bih = bih; P.bhh = bhh; P.bk = bk; P.bv = bv;
  P.h0b = h0b; P.c0f = c0f;
  P.ping = ping;
  P.WihT = WihT; P.WhhT = WhhT; P.WqkvT = WqkvT;
  P.Qx = Qx; P.Kx = Kx; P.Vx = Vx;
  P.rowbuf = rowbuf; P.hsb = hsb;
  P.out = d_out;
  P.ctr = ctr; P.flag = flag;
  scan_kernel<<<dim3(240), dim3(64), 0, stream>>>(P);
}

// Round 6
// 7975.984 us; speedup vs baseline: 2.3997x; 2.0203x over previous
//
#include <hip/hip_runtime.h>
#include <hip/hip_bf16.h>

#define TLEN 512
#define NB   32
#define HID  768
#define G4   3072
#define NBLK 272
#define ARR  34   // NBLK / 8 arrivals per counter line

typedef __attribute__((ext_vector_type(8))) short bf16x8;
typedef __attribute__((ext_vector_type(4))) float f32x4;
typedef unsigned short u16;
typedef unsigned int u32;
typedef unsigned long long u64;

__device__ __forceinline__ float bf2f(u16 u) {
  u32 t = ((u32)u) << 16; float f; __builtin_memcpy(&f, &t, 4); return f;
}
__device__ __forceinline__ u16 f2bf(float f) {
  u32 t; __builtin_memcpy(&t, &f, 4);
  u32 r = t + 0x7FFFu + ((t >> 16) & 1u);
  return (u16)(r >> 16);
}
// dual-dtype scalar loads: f!=0 -> input buffer is fp32, else packed bf16
__device__ __forceinline__ u16 ldbf(const void* p, size_t i, u32 f) {
  return f ? f2bf(((const float*)p)[i]) : ((const u16*)p)[i];
}
__device__ __forceinline__ float ldf(const void* p, size_t i, u32 f) {
  return f ? ((const float*)p)[i] : bf2f(((const u16*)p)[i]);
}
__device__ __forceinline__ float sigm(float x) { return 1.0f / (1.0f + __expf(-x)); }
__device__ __forceinline__ float tanh_(float x) { return 1.0f - 2.0f / (1.0f + __expf(2.0f * x)); }

// ---- agent-scope (cross-XCD coherent) accesses: bypass stale L2 ----
__device__ __forceinline__ u64 cld64(const u16* p) {
  return __hip_atomic_load((const u64*)p, __ATOMIC_RELAXED, __HIP_MEMORY_SCOPE_AGENT);
}
__device__ __forceinline__ void cst64(u16* p, u64 v) {
  __hip_atomic_store((u64*)p, v, __ATOMIC_RELAXED, __HIP_MEMORY_SCOPE_AGENT);
}
__device__ __forceinline__ bf16x8 cld128(const u16* p) {
  union { u64 q[2]; bf16x8 v; } u;
  u.q[0] = cld64(p); u.q[1] = cld64(p + 4);
  return u.v;
}

// ---------------- prologue: dtype sniff + h0/c0 conversion -------------------
__global__ __launch_bounds__(256) void prologue(const void* __restrict__ x,
                                                const void* __restrict__ h0,
                                                const void* __restrict__ c0,
                                                u32* __restrict__ flag,
                                                u16* __restrict__ h0b,
                                                float* __restrict__ c0f) {
  __shared__ u32 sflag;
  if (threadIdx.x == 0) {
    const u32* w = (const u32*)x;
    int cnt = 0;
    for (int m = 0; m < 256; ++m) {
      u32 e = ((w[m] & 0xFFFFu) >> 7) & 0xFFu;
      cnt += (e >= 100u && e <= 140u) ? 1 : 0;
    }
    sflag = (cnt >= 128) ? 0u : 1u;  // 1 = fp32 inputs
    flag[0] = sflag;
  }
  __syncthreads();
  const u32 f = sflag;
  for (int i = threadIdx.x; i < NB * HID; i += 256) {
    h0b[i] = ldbf(h0, i, f);
    c0f[i] = ldf(c0, i, f);
  }
}

// ---------------- transpose (R x C row-major -> C x R, emits bf16) ----------
__global__ __launch_bounds__(256) void transpose_any(const void* __restrict__ in,
                                                     u16* __restrict__ out, int R, int C,
                                                     const u32* __restrict__ flag) {
  const u32 f = flag[0];
  __shared__ u16 tile[64][65];
  int c0 = blockIdx.x * 64, r0 = blockIdx.y * 64;
  int tx = threadIdx.x & 63, ty = threadIdx.x >> 6;
#pragma unroll
  for (int j = 0; j < 16; ++j) {
    int r = ty + 4 * j;
    tile[r][tx] = ldbf(in, (size_t)(r0 + r) * C + c0 + tx, f);
  }
  __syncthreads();
#pragma unroll
  for (int j = 0; j < 16; ++j) {
    int r = ty + 4 * j;
    out[(size_t)(c0 + r) * R + r0 + tx] = tile[tx][r];
  }
}

// ---------------- QKV precompute: [16384 x 768] @ [768 x 2304] --------------
__global__ __launch_bounds__(256) void qkv_gemm(const void* __restrict__ X, const u16* __restrict__ WT,
                                                const void* __restrict__ bq, const void* __restrict__ bk,
                                                const void* __restrict__ bv,
                                                u16* __restrict__ Qx, u16* __restrict__ Kx,
                                                u16* __restrict__ Vx, const u32* __restrict__ flag) {
  const u32 f = flag[0];
  __shared__ __align__(16) u16 As[128][40];
  __shared__ __align__(16) u16 Bs[128][40];
  const int m0 = blockIdx.x * 128;
  const int n0 = blockIdx.y * 128;
  const int tid = threadIdx.x;
  const int lane = tid & 63, w = tid >> 6;
  const int l15 = lane & 15, l4 = lane >> 4;
  f32x4 zero4 = {0.f, 0.f, 0.f, 0.f};
  f32x4 acc[2][8];
#pragma unroll
  for (int h = 0; h < 2; ++h)
#pragma unroll
    for (int nt = 0; nt < 8; ++nt) acc[h][nt] = zero4;
  const int srow = tid >> 1, skp = (tid & 1) * 16;
  for (int k0 = 0; k0 < 768; k0 += 32) {
    __syncthreads();
    if (f) {
      const float* Xf = (const float*)X + (size_t)(m0 + srow) * 768 + k0 + skp;
#pragma unroll
      for (int q = 0; q < 16; ++q) As[srow][skp + q] = f2bf(Xf[q]);
    } else {
      const u16* Xh = (const u16*)X + (size_t)(m0 + srow) * 768 + k0 + skp;
      *(bf16x8*)&As[srow][skp]     = *(const bf16x8*)(Xh);
      *(bf16x8*)&As[srow][skp + 8] = *(const bf16x8*)(Xh + 8);
    }
    *(bf16x8*)&Bs[srow][skp]     = *(const bf16x8*)(WT + (size_t)(n0 + srow) * 768 + k0 + skp);
    *(bf16x8*)&Bs[srow][skp + 8] = *(const bf16x8*)(WT + (size_t)(n0 + srow) * 768 + k0 + skp + 8);
    __syncthreads();
    const int kl = 8 * l4;
    bf16x8 a0 = *(const bf16x8*)&As[32 * w + l15][kl];
    bf16x8 a1 = *(const bf16x8*)&As[32 * w + 16 + l15][kl];
#pragma unroll
    for (int nt = 0; nt < 8; ++nt) {
      bf16x8 b = *(const bf16x8*)&Bs[16 * nt + l15][kl];
      acc[0][nt] = __builtin_amdgcn_mfma_f32_16x16x32_bf16(a0, b, acc[0][nt], 0, 0, 0);
      acc[1][nt] = __builtin_amdgcn_mfma_f32_16x16x32_bf16(a1, b, acc[1][nt], 0, 0, 0);
    }
  }
#pragma unroll
  for (int h = 0; h < 2; ++h)
#pragma unroll
    for (int nt = 0; nt < 8; ++nt)
#pragma unroll
      for (int r = 0; r < 4; ++r) {
        const int m = m0 + 32 * w + 16 * h + 4 * l4 + r;
        const int n = n0 + 16 * nt + l15;
        float bias; u16* dst;
        if (n < 768)       { bias = ldf(bq, n, f);        dst = Qx + (size_t)m * 768 + n; }
        else if (n < 1536) { bias = ldf(bk, n - 768, f);  dst = Kx + (size_t)m * 768 + (n - 768); }
        else               { bias = ldf(bv, n - 1536, f); dst = Vx + (size_t)m * 768 + (n - 1536); }
        *dst = f2bf(acc[h][nt][r] + bias);
      }
}

// ---------------- persistent sequential scan (1 barrier per step) ------------
// Interval i: gates compute h_i from (row_i, h_{i-1}); kv project row_i ->
// Kx[i]/Vx[i]; attn compute row_{i+1} (uses Kx/Vx rows !=i, or polls kvctr for
// the rare idx==i). rowbuf and h are parity double-buffered so every
// cross-wave RAW/WAR pair is separated by >=1 barrier.
struct ScanParams {
  const void *x, *bih, *bhh, *bk, *bv;
  const u16 *h0b;
  const float *c0f;
  const int* ping;
  const u16 *WihT, *WhhT, *WqkvT;
  const u16 *Qx;
  u16 *Kx, *Vx;
  u16 *rowbuf, *hsb;
  void* out;
  u32 *ctr;       // [0..224 step32]=arrival lines, [256]=epoch, [320]=kvctr
  const u32* flag;
};

// Arrivals: 8 lines, ARR RMWs each (uncontended — nobody polls these except
// block 0). Block 0 detects completion and publishes epoch on a separate line;
// everyone polls epoch via a single lane-0 load + shfl broadcast.
__device__ __forceinline__ void gbarrier(u32* ctr, int bid, u32 z) {
  __builtin_amdgcn_s_waitcnt(0);
  if (threadIdx.x == 0)
    __hip_atomic_fetch_add(&ctr[(bid & 7) * 32], 1u, __ATOMIC_RELAXED, __HIP_MEMORY_SCOPE_AGENT);
  if (bid == 0) {
    for (;;) {
      u32 mine = ARR * z;
      if (threadIdx.x < 8)
        mine = __hip_atomic_load(&ctr[threadIdx.x * 32], __ATOMIC_RELAXED, __HIP_MEMORY_SCOPE_AGENT);
      if (__all(mine >= ARR * z)) break;
      __builtin_amdgcn_s_sleep(1);
    }
    if (threadIdx.x == 0)
      __hip_atomic_store(&ctr[256], z, __ATOMIC_RELAXED, __HIP_MEMORY_SCOPE_AGENT);
  }
  for (;;) {
    u32 e = 0;
    if (threadIdx.x == 0)
      e = __hip_atomic_load(&ctr[256], __ATOMIC_RELAXED, __HIP_MEMORY_SCOPE_AGENT);
    e = __shfl(e, 0);
    if (e >= z) break;
    __builtin_amdgcn_s_sleep(2);
  }
  asm volatile("" ::: "memory");
}

__global__ __launch_bounds__(64, 1) void scan_kernel(ScanParams P) {
  const int bid = blockIdx.x;
  const int lane = threadIdx.x;
  const int l15 = lane & 15, l4 = lane >> 4;
  const u32 f = P.flag[0];
  u32 z = 1;

  if (bid < 192) {
    // ------- gates wave: 16 tile-cols = {jb+jl} x {i,f,g,o blocks}, K=1536 -----
    const int jb = 4 * bid;
    const int q_ = l15 >> 2, jl = l15 & 3;
    const int colW = 768 * q_ + jb + jl;
    bf16x8 Bfr[48];
#pragma unroll
    for (int s = 0; s < 48; ++s) {
      int k = 32 * s + 8 * l4;
      const u16* src = (s < 24) ? (P.WihT + (size_t)colW * HID + k)
                                : (P.WhhT + (size_t)colW * HID + (k - 768));
      Bfr[s] = *(const bf16x8*)src;
    }
    const float biasv = ldf(P.bih, colW, f) + ldf(P.bhh, colW, f);
    const int cb = lane >> 1, cj = 2 * (lane & 1);
    float cst0 = P.c0f[(size_t)cb * HID + jb + cj];
    float cst1 = P.c0f[(size_t)cb * HID + jb + cj + 1];
    __shared__ float gbuf[32][4][4];
    __shared__ u16 htile[32][4];
    gbarrier(P.ctr, bid, z); ++z;   // prologue: row_0 published

    for (int i = 0; i < TLEN; ++i) {
      const u16* rowp = P.rowbuf + (size_t)(i & 1) * NB * HID;
      const u16* hp = (i == 0) ? P.h0b : (P.hsb + (size_t)((i - 1) & 1) * NB * HID);
      f32x4 acc0 = {0.f, 0.f, 0.f, 0.f}, acc1 = {0.f, 0.f, 0.f, 0.f};
#pragma unroll
      for (int s = 0; s < 48; ++s) {
        int k = 32 * s + 8 * l4;
        const u16* base = (s < 24) ? (rowp + k) : (hp + (k - 768));
        bf16x8 a0 = cld128(base + (size_t)l15 * HID);
        bf16x8 a1 = cld128(base + (size_t)(l15 + 16) * HID);
        acc0 = __builtin_amdgcn_mfma_f32_16x16x32_bf16(a0, Bfr[s], acc0, 0, 0, 0);
        acc1 = __builtin_amdgcn_mfma_f32_16x16x32_bf16(a1, Bfr[s], acc1, 0, 0, 0);
      }
#pragma unroll
      for (int r = 0; r < 4; ++r) {
        gbuf[4 * l4 + r][q_][jl] = acc0[r] + biasv;
        gbuf[16 + 4 * l4 + r][q_][jl] = acc1[r] + biasv;
      }
      __syncthreads();
      float ig0 = gbuf[cb][0][cj],     fg0 = gbuf[cb][1][cj];
      float gg0 = gbuf[cb][2][cj],     og0 = gbuf[cb][3][cj];
      float ig1 = gbuf[cb][0][cj + 1], fg1 = gbuf[cb][1][cj + 1];
      float gg1 = gbuf[cb][2][cj + 1], og1 = gbuf[cb][3][cj + 1];
      __syncthreads();
      cst0 = sigm(fg0) * cst0 + sigm(ig0) * tanh_(gg0);
      cst1 = sigm(fg1) * cst1 + sigm(ig1) * tanh_(gg1);
      float h0v = sigm(og0) * tanh_(cst0);
      float h1v = sigm(og1) * tanh_(cst1);
      htile[cb][cj] = f2bf(h0v); htile[cb][cj + 1] = f2bf(h1v);
      __syncthreads();
      if (lane < 32) {
        u64 hv; __builtin_memcpy(&hv, &htile[lane][0], 8);
        cst64(P.hsb + (size_t)(i & 1) * NB * HID + (size_t)lane * HID + jb, hv);
      }
      const size_t o1 = (size_t)i * NB * HID + (size_t)cb * HID + jb + cj;
      if (f) { float* O = (float*)P.out; O[o1] = h0v; O[o1 + 1] = h1v; }
      else   { u16*   O = (u16*)P.out;   O[o1] = f2bf(h0v); O[o1 + 1] = f2bf(h1v); }
      if (i == TLEN - 1) {
        const size_t oh = (size_t)TLEN * NB * HID + (size_t)cb * HID + jb + cj;
        const size_t oc = (size_t)(TLEN + 1) * NB * HID + (size_t)cb * HID + jb + cj;
        if (f) { float* O = (float*)P.out; O[oh] = h0v; O[oh + 1] = h1v; O[oc] = cst0; O[oc + 1] = cst1; }
        else   { u16*   O = (u16*)P.out;   O[oh] = f2bf(h0v); O[oh + 1] = f2bf(h1v);
                 O[oc] = f2bf(cst0); O[oc + 1] = f2bf(cst1); }
      }
      gbarrier(P.ctr, bid, z); ++z;
    }
  } else if (bid < 240) {
    // ------- k/v projection wave: 32 cols of K or V, K-dim 768 -----------------
    const int v = bid - 192;
    const int col0 = 32 * v;
    const bool isV = (col0 >= 768);
    const u16* Wt = P.WqkvT + (size_t)(768 + col0) * HID;
    const int oc0 = isV ? (col0 - 768) : col0;
    u16* obase = isV ? P.Vx : P.Kx;
    const void* bias_src = isV ? P.bv : P.bk;
    const float bias0 = ldf(bias_src, oc0 + l15, f);
    const float bias1 = ldf(bias_src, oc0 + 16 + l15, f);
    bf16x8 Bfr[48];
#pragma unroll
    for (int s = 0; s < 24; ++s) {
      int k = 32 * s + 8 * l4;
      Bfr[2 * s]     = *(const bf16x8*)(Wt + (size_t)l15 * HID + k);
      Bfr[2 * s + 1] = *(const bf16x8*)(Wt + (size_t)(16 + l15) * HID + k);
    }
    __shared__ __align__(8) u16 tile[32][32];
    gbarrier(P.ctr, bid, z); ++z;   // prologue

    for (int i = 0; i < TLEN; ++i) {
      const u16* rowp = P.rowbuf + (size_t)(i & 1) * NB * HID;
      f32x4 a00 = {0.f,0.f,0.f,0.f}, a01 = {0.f,0.f,0.f,0.f};
      f32x4 a10 = {0.f,0.f,0.f,0.f}, a11 = {0.f,0.f,0.f,0.f};
#pragma unroll
      for (int s = 0; s < 24; ++s) {
        int k = 32 * s + 8 * l4;
        bf16x8 r0 = cld128(rowp + (size_t)l15 * HID + k);
        bf16x8 r1 = cld128(rowp + (size_t)(l15 + 16) * HID + k);
        a00 = __builtin_amdgcn_mfma_f32_16x16x32_bf16(r0, Bfr[2 * s],     a00, 0, 0, 0);
        a01 = __builtin_amdgcn_mfma_f32_16x16x32_bf16(r0, Bfr[2 * s + 1], a01, 0, 0, 0);
        a10 = __builtin_amdgcn_mfma_f32_16x16x32_bf16(r1, Bfr[2 * s],     a10, 0, 0, 0);
        a11 = __builtin_amdgcn_mfma_f32_16x16x32_bf16(r1, Bfr[2 * s + 1], a11, 0, 0, 0);
      }
#pragma unroll
      for (int r = 0; r < 4; ++r) {
        int b0 = 4 * l4 + r;
        tile[b0][l15]           = f2bf(a00[r] + bias0);
        tile[b0][16 + l15]      = f2bf(a01[r] + bias1);
        tile[16 + b0][l15]      = f2bf(a10[r] + bias0);
        tile[16 + b0][16 + l15] = f2bf(a11[r] + bias1);
      }
      __syncthreads();
      {
        u16* ob = obase + (size_t)i * NB * HID + oc0;
        const int row = lane >> 1, ch = (lane & 1) * 16;
#pragma unroll
        for (int q = 0; q < 4; ++q) {
          u64 w8; __builtin_memcpy(&w8, &tile[row][ch + 4 * q], 8);
          cst64(ob + (size_t)row * HID + ch + 4 * q, w8);
        }
      }
      __syncthreads();
      // publish "Kx/Vx row i complete" for the rare attn idx==i dependency
      __builtin_amdgcn_s_waitcnt(0);
      if (lane == 0)
        __hip_atomic_fetch_add(&P.ctr[320], 1u, __ATOMIC_RELAXED, __HIP_MEMORY_SCOPE_AGENT);
      gbarrier(P.ctr, bid, z); ++z;
    }
  } else {
    // ------- attention wave: batch b computes row_{i+1} during interval i ------
    const int b = bid - 240;
    __shared__ __align__(8) u16 sbuf[3][HID];
    {  // prologue: row_0 = x[0] (t=0 mask false)
      const size_t xoff = (size_t)b * HID + 12 * lane;
      u16* orow = P.rowbuf + (size_t)b * HID + 12 * lane;
#pragma unroll
      for (int q = 0; q < 3; ++q) {
        u16 e[4];
#pragma unroll
        for (int t2 = 0; t2 < 4; ++t2) e[t2] = ldbf(P.x, xoff + 4 * q + t2, f);
        u64 w8; __builtin_memcpy(&w8, e, 8);
        cst64(orow + 4 * q, w8);
      }
    }
    gbarrier(P.ctr, bid, z); ++z;   // prologue

    for (int i = 0; i < TLEN; ++i) {
      if (i < TLEN - 1) {
        const int t = i + 1;
        const int p = P.ping[(size_t)b * TLEN + t];
        u16* orow = P.rowbuf + (size_t)(t & 1) * NB * HID + (size_t)b * HID;
        if (p == 0) {  // mask false -> row = x[t]
          const size_t xoff = ((size_t)t * NB + b) * HID + 12 * lane;
#pragma unroll
          for (int q = 0; q < 3; ++q) {
            u16 e[4];
#pragma unroll
            for (int t2 = 0; t2 < 4; ++t2) e[t2] = ldbf(P.x, xoff + 4 * q + t2, f);
            u64 w8; __builtin_memcpy(&w8, e, 8);
            cst64(orow + 12 * lane + 4 * q, w8);
          }
        } else {
          const int idx = p - 1;
          if (idx == i) {  // produced this interval: wait for all 48 kv waves
            while (__hip_atomic_load(&P.ctr[320], __ATOMIC_RELAXED, __HIP_MEMORY_SCOPE_AGENT) <
                   48u * (u32)(i + 1)) {
              __builtin_amdgcn_s_sleep(2);
            }
            asm volatile("" ::: "memory");
          }
          const u16* kL = P.Kx + ((size_t)idx * NB + b) * HID;
          const u16* vL = P.Vx + ((size_t)idx * NB + b) * HID;
#pragma unroll
          for (int q = 0; q < 3; ++q) {
            *(u64*)&sbuf[0][12 * lane + 4 * q] = cld64(kL + 12 * lane + 4 * q);
            *(u64*)&sbuf[1][12 * lane + 4 * q] = cld64(vL + 12 * lane + 4 * q);
          }
          const u16* qp = P.Qx + ((size_t)t * NB + b) * HID;  // never rewritten
          const u16* kR = P.Kx + ((size_t)t * NB + b) * HID;  // row t untouched until interval t
          const u16* vR = P.Vx + ((size_t)t * NB + b) * HID;
          __syncthreads();
          float d0[12], d1[12];
#pragma unroll
          for (int j = 0; j < 12; ++j) {
            float qv = bf2f(qp[64 * j + lane]);
            d0[j] = qv * bf2f(sbuf[0][64 * j + lane]);
            d1[j] = qv * bf2f(kR[64 * j + lane]);
          }
#pragma unroll
          for (int m = 32; m > 0; m >>= 1) {
#pragma unroll
            for (int j = 0; j < 12; ++j) {
              d0[j] += __shfl_xor(d0[j], m);
              d1[j] += __shfl_xor(d1[j], m);
            }
          }
#pragma unroll
          for (int j = 0; j < 12; ++j) {
            float pw0 = sigm((d0[j] - d1[j]) * 0.125f);  // softmax over 2 keys
            float ov = pw0 * bf2f(sbuf[1][64 * j + lane]) + (1.0f - pw0) * bf2f(vR[64 * j + lane]);
            sbuf[2][64 * j + lane] = f2bf(ov);
          }
          __syncthreads();
#pragma unroll
          for (int q = 0; q < 3; ++q) {
            u64 w8; __builtin_memcpy(&w8, &sbuf[2][12 * lane + 4 * q], 8);
            cst64(orow + 12 * lane + 4 * q, w8);
          }
        }
      }
      gbarrier(P.ctr, bid, z); ++z;
    }
  }
}

extern "C" void kernel_launch(void* const* d_in, const int* in_sizes, int n_in,
                              void* d_out, int out_size, void* d_ws, size_t ws_size,
                              hipStream_t stream) {
  const void* x   = d_in[0];
  const int* ping = (const int*)d_in[1];
  const void* h0  = d_in[2];
  const void* c0  = d_in[3];
  const void* wih = d_in[4];
  const void* whh = d_in[5];
  const void* bih = d_in[6];
  const void* bhh = d_in[7];
  const void* wq  = d_in[8];
  const void* bq  = d_in[9];
  const void* wk  = d_in[10];
  const void* bk  = d_in[11];
  const void* wv  = d_in[12];
  const void* bv  = d_in[13];
  (void)in_sizes; (void)n_in; (void)out_size; (void)ws_size;  // needs ~90 MB ws

  char* ws = (char*)d_ws;
  size_t off = 0;
  auto walloc = [&](size_t b) { char* p = ws + off; off += (b + 255) & ~(size_t)255; return p; };
  u32* ctr    = (u32*)walloc(2048);
  u32* flag   = ctr + 400;  // clear of lines 0..224, epoch 256, kvctr 320
  u16* WqkvT  = (u16*)walloc((size_t)2304 * 768 * 2);
  u16* WihT   = (u16*)walloc((size_t)3072 * 768 * 2);
  u16* WhhT   = (u16*)walloc((size_t)3072 * 768 * 2);
  u16* Qx     = (u16*)walloc((size_t)TLEN * NB * HID * 2);
  u16* Kx     = (u16*)walloc((size_t)TLEN * NB * HID * 2);
  u16* Vx     = (u16*)walloc((size_t)TLEN * NB * HID * 2);
  u16* rowbuf = (u16*)walloc((size_t)2 * NB * HID * 2);
  u16* h0b    = (u16*)walloc((size_t)NB * HID * 2);
  float* c0f  = (float*)walloc((size_t)NB * HID * 4);
  u16* hsb    = (u16*)walloc((size_t)2 * NB * HID * 2);

  hipMemsetAsync(ctr, 0, 2048, stream);
  prologue<<<1, 256, 0, stream>>>(x, h0, c0, flag, h0b, c0f);
  transpose_any<<<dim3(12, 12), 256, 0, stream>>>(wq, WqkvT, 768, 768, flag);
  transpose_any<<<dim3(12, 12), 256, 0, stream>>>(wk, WqkvT + (size_t)768 * 768, 768, 768, flag);
  transpose_any<<<dim3(12, 12), 256, 0, stream>>>(wv, WqkvT + (size_t)1536 * 768, 768, 768, flag);
  transpose_any<<<dim3(48, 12), 256, 0, stream>>>(wih, WihT, 768, 3072, flag);
  transpose_any<<<dim3(48, 12), 256, 0, stream>>>(whh, WhhT, 768, 3072, flag);
  qkv_gemm<<<dim3(128, 18), 256, 0, stream>>>(x, WqkvT, bq, bk, bv, Qx, Kx, Vx, flag);

  ScanParams P;
  P.x = x; P.bih = bih; P.bhh = bhh; P.bk = bk; P.bv = bv;
  P.h0b = h0b; P.c0f = c0f;
  P.ping = ping;
  P.WihT = WihT; P.WhhT = WhhT; P.WqkvT = WqkvT;
  P.Qx = Qx; P.Kx = Kx; P.Vx = Vx;
  P.rowbuf = rowbuf; P.hsb = hsb;
  P.out = d_out;
  P.ctr = ctr; P.flag = flag;
  scan_kernel<<<dim3(NBLK), dim3(64), 0, stream>>>(P);
}